// Round 2
// baseline (2162.464 us; speedup 1.0000x reference)
//
#include <hip/hip_runtime.h>
#include <math.h>

#define BB 8
#define LL 2048
#define MM 4096
#define DD 512
#define NQ (BB*LL)           // 16384 query rows
#define NM (BB*MM)           // 32768 memory rows
#define TOPK 5
#define TOPS 6               // candidates kept per split
#define MSPLIT 4
#define NC (MSPLIT*TOPS)     // 24 candidates per row
#define MRANGE (MM/MSPLIT)   // 1024
#define BQ 128
#define BMT 128
#define BK 32
#define LDSP (BK+4)

// workspace layout (4-byte units)
#define WS_RM 0                       // NM floats: 1/||mem row||
#define WS_CI (WS_RM + NM)            // NQ*NC ints: candidate indices

#define NEG_INF (-3.402823466e38f)

// ---------------- kernel 1: reciprocal norms of memory rows ----------------
__global__ void k_rnorm(const float* __restrict__ mem, float* __restrict__ wsf) {
  const int gwave = (blockIdx.x * blockDim.x + threadIdx.x) >> 6;
  const int lane  = threadIdx.x & 63;
  if (gwave >= NM) return;
  const float4* r4 = (const float4*)(mem + (size_t)gwave * DD) + lane * 2;
  float4 a = r4[0];
  float4 c = r4[1];
  float ss = a.x*a.x + a.y*a.y + a.z*a.z + a.w*a.w
           + c.x*c.x + c.y*c.y + c.z*c.z + c.w*c.w;
  #pragma unroll
  for (int off = 1; off < 64; off <<= 1) ss += __shfl_xor(ss, off, 64);
  if (lane == 0) wsf[WS_RM + gwave] = 1.0f / fmaxf(sqrtf(ss), 1e-12f);
}

// ---------------- kernel 2: fp32 sim GEMM + per-split top-6 screening ----------------
// block: 256 threads as (tx 0..15, ty 0..15); tile 128q x 128m; per-thread 8q x 8m
__launch_bounds__(256, 2)
__global__ void k_simtopk(const float* __restrict__ enc, const float* __restrict__ mem,
                          const float* __restrict__ wsf, int* __restrict__ wsi) {
  __shared__ float enc_s[BQ * LDSP];
  __shared__ float mem_s[BMT * LDSP];
  const int tid = threadIdx.x;
  const int tx = tid & 15;
  const int ty = tid >> 4;
  const int qb = blockIdx.x >> 2;
  const int split = blockIdx.x & 3;
  const int qbase = qb * BQ;
  const int b = qbase / LL;
  const int m0 = split * MRANGE;
  const float* encB = enc + (size_t)qbase * DD;
  const float* memB = mem + ((size_t)b * MM + m0) * DD;

  float tv[8][TOPS];
  int   ti[8][TOPS];
  #pragma unroll
  for (int qi = 0; qi < 8; ++qi)
    #pragma unroll
    for (int s = 0; s < TOPS; ++s) { tv[qi][s] = NEG_INF; ti[qi][s] = 0; }

  #pragma unroll 1
  for (int mt = 0; mt < MRANGE/BMT; ++mt) {
    float acc[8][8];
    #pragma unroll
    for (int qi = 0; qi < 8; ++qi)
      #pragma unroll
      for (int mj = 0; mj < 8; ++mj) acc[qi][mj] = 0.0f;

    #pragma unroll 1
    for (int kt = 0; kt < DD/BK; ++kt) {
      #pragma unroll
      for (int t = 0; t < 4; ++t) {
        const int i = t*256 + tid;
        const int r = i >> 3, c4 = i & 7;
        *(float4*)&enc_s[r*LDSP + c4*4] =
            *(const float4*)&encB[(size_t)r*DD + kt*BK + c4*4];
        *(float4*)&mem_s[r*LDSP + c4*4] =
            *(const float4*)&memB[(size_t)(mt*BMT + r)*DD + kt*BK + c4*4];
      }
      __syncthreads();
      #pragma unroll 2
      for (int kk = 0; kk < BK; kk += 4) {
        float4 mv[8];
        #pragma unroll
        for (int mj = 0; mj < 8; ++mj)
          mv[mj] = *(const float4*)&mem_s[(tx + mj*16)*LDSP + kk];
        #pragma unroll
        for (int qi = 0; qi < 8; ++qi) {
          const float4 ev = *(const float4*)&enc_s[(ty + qi*16)*LDSP + kk];
          #pragma unroll
          for (int mj = 0; mj < 8; ++mj) {
            acc[qi][mj] = fmaf(ev.x, mv[mj].x, acc[qi][mj]);
            acc[qi][mj] = fmaf(ev.y, mv[mj].y, acc[qi][mj]);
            acc[qi][mj] = fmaf(ev.z, mv[mj].z, acc[qi][mj]);
            acc[qi][mj] = fmaf(ev.w, mv[mj].w, acc[qi][mj]);
          }
        }
      }
      __syncthreads();
    }

    // epilogue: scale by memory norm only (enc norm is a per-row positive
    // constant -> ordering-invariant), insert into running top-6
    #pragma unroll
    for (int mj = 0; mj < 8; ++mj) {
      const int gm = m0 + mt*BMT + tx + mj*16;
      const float rm = wsf[WS_RM + b*MM + gm];
      #pragma unroll
      for (int qi = 0; qi < 8; ++qi) {
        float nv = acc[qi][mj] * rm;
        int   ni = gm;
        #pragma unroll
        for (int s = 0; s < TOPS; ++s) {
          const bool g = nv > tv[qi][s];
          const float ov = tv[qi][s]; const int oi = ti[qi][s];
          tv[qi][s] = g ? nv : ov;  ti[qi][s] = g ? ni : oi;
          nv = g ? ov : nv;         ni = g ? oi : ni;
        }
      }
    }
  }

  // merge the 16 per-lane lists of each q across tx (same wave: xor of low 4 lane bits)
  #pragma unroll
  for (int step = 1; step < 16; step <<= 1) {
    #pragma unroll
    for (int qi = 0; qi < 8; ++qi) {
      float fv[TOPS]; int fi[TOPS];
      #pragma unroll
      for (int s = 0; s < TOPS; ++s) {
        fv[s] = __shfl_xor(tv[qi][s], step, 64);
        fi[s] = __shfl_xor(ti[qi][s], step, 64);
      }
      #pragma unroll
      for (int s = 0; s < TOPS; ++s) {
        float nv = fv[s]; int ni = fi[s];
        #pragma unroll
        for (int s2 = 0; s2 < TOPS; ++s2) {
          const bool g = (nv > tv[qi][s2]) || (nv == tv[qi][s2] && ni < ti[qi][s2]);
          const float ov = tv[qi][s2]; const int oi = ti[qi][s2];
          tv[qi][s2] = g ? nv : ov;  ti[qi][s2] = g ? ni : oi;
          nv = g ? ov : nv;          ni = g ? oi : ni;
        }
      }
    }
  }

  if (tx == 0) {
    #pragma unroll
    for (int qi = 0; qi < 8; ++qi) {
      const int q = qbase + ty + qi*16;
      #pragma unroll
      for (int s = 0; s < TOPS; ++s)
        wsi[WS_CI + (q*MSPLIT + split)*TOPS + s] = ti[qi][s];
    }
  }
}

// ---------------- kernel 3: fp64 rescore 24 candidates, exact top-5, gather, mean, add ----------------
__global__ void k_out(const float* __restrict__ enc, const float* __restrict__ mem,
                      const float* __restrict__ wsf, const int* __restrict__ wsi,
                      float* __restrict__ out) {
  const int row  = (blockIdx.x * blockDim.x + threadIdx.x) >> 6;  // one wave per row
  const int lane = threadIdx.x & 63;
  if (row >= NQ) return;
  const int b = row >> 11;

  int ci[NC];
  #pragma unroll
  for (int e = 0; e < NC; ++e) ci[e] = wsi[WS_CI + row*NC + e];

  const float* er = enc + (size_t)row * DD;
  const float* mb = mem + (size_t)b * MM * DD;
  const int d0 = lane * 8;
  const float4 e0 = *(const float4*)(er + d0);
  const float4 e1 = *(const float4*)(er + d0 + 4);
  double ed[8] = {(double)e0.x,(double)e0.y,(double)e0.z,(double)e0.w,
                  (double)e1.x,(double)e1.y,(double)e1.z,(double)e1.w};

  // exact (fp64) partial dot for each candidate over this lane's 8 dims
  double ps[NC];
  #pragma unroll
  for (int e = 0; e < NC; ++e) {
    const float* mr = mb + (size_t)ci[e] * DD + d0;
    const float4 x0 = *(const float4*)mr;
    const float4 x1 = *(const float4*)(mr + 4);
    double s = ed[0]*(double)x0.x;
    s = fma(ed[1],(double)x0.y,s); s = fma(ed[2],(double)x0.z,s);
    s = fma(ed[3],(double)x0.w,s); s = fma(ed[4],(double)x1.x,s);
    s = fma(ed[5],(double)x1.y,s); s = fma(ed[6],(double)x1.z,s);
    s = fma(ed[7],(double)x1.w,s);
    ps[e] = s;
  }
  // butterfly reduce across the wave (all lanes end with full sums)
  #pragma unroll
  for (int off = 1; off < 64; off <<= 1) {
    #pragma unroll
    for (int e = 0; e < NC; ++e) ps[e] += __shfl_xor(ps[e], off, 64);
  }
  // final comparable scores: dot * (1/||m||)  (enc norm is row-constant)
  double fv[NC];
  #pragma unroll
  for (int e = 0; e < NC; ++e) fv[e] = ps[e] * (double)wsf[WS_RM + b*MM + ci[e]];

  // exact top-5 by (value desc, index asc) via rank counting (static indexing only)
  int sel[TOPK];
  #pragma unroll
  for (int t = 0; t < TOPK; ++t) sel[t] = 0;
  #pragma unroll
  for (int e = 0; e < NC; ++e) {
    int r = 0;
    #pragma unroll
    for (int e2 = 0; e2 < NC; ++e2) {
      const bool beats = (fv[e2] > fv[e]) || (fv[e2] == fv[e] && ci[e2] < ci[e]);
      r += beats ? 1 : 0;
    }
    #pragma unroll
    for (int t = 0; t < TOPK; ++t) if (r == t) sel[t] = ci[e];
  }

  float4 a0 = make_float4(0.f,0.f,0.f,0.f);
  float4 a1 = make_float4(0.f,0.f,0.f,0.f);
  #pragma unroll
  for (int t = 0; t < TOPK; ++t) {
    const float* mr = mb + (size_t)sel[t] * DD + d0;
    const float4 x0 = *(const float4*)mr;
    const float4 x1 = *(const float4*)(mr + 4);
    a0.x += x0.x; a0.y += x0.y; a0.z += x0.z; a0.w += x0.w;
    a1.x += x1.x; a1.y += x1.y; a1.z += x1.z; a1.w += x1.w;
  }
  float4 o0, o1;
  o0.x = e0.x + a0.x / 5.0f; o0.y = e0.y + a0.y / 5.0f;
  o0.z = e0.z + a0.z / 5.0f; o0.w = e0.w + a0.w / 5.0f;
  o1.x = e1.x + a1.x / 5.0f; o1.y = e1.y + a1.y / 5.0f;
  o1.z = e1.z + a1.z / 5.0f; o1.w = e1.w + a1.w / 5.0f;
  *(float4*)(out + (size_t)row*DD + d0)     = o0;
  *(float4*)(out + (size_t)row*DD + d0 + 4) = o1;
}

extern "C" void kernel_launch(void* const* d_in, const int* in_sizes, int n_in,
                              void* d_out, int out_size, void* d_ws, size_t ws_size,
                              hipStream_t stream) {
  const float* enc = (const float*)d_in[0];
  const float* mem = (const float*)d_in[1];
  float* out = (float*)d_out;
  float* wsf = (float*)d_ws;
  int*   wsi = (int*)d_ws;

  k_rnorm<<<dim3(NM / 4), dim3(256), 0, stream>>>(mem, wsf);
  k_simtopk<<<dim3((NQ / BQ) * MSPLIT), dim3(256), 0, stream>>>(enc, mem, wsf, wsi);
  k_out<<<dim3(NQ / 4), dim3(256), 0, stream>>>(enc, mem, wsf, wsi, out);
}

// Round 3
// 385.575 us; speedup vs baseline: 5.6084x; 5.6084x over previous
//
#include <hip/hip_runtime.h>
#include <math.h>

#define BB 8
#define LL 2048
#define MM 4096
#define DD 512
#define NQ (BB*LL)           // 16384 query rows
#define NM (BB*MM)           // 32768 memory rows
#define TOPK 5
#define TOPS 8               // candidates kept per split
#define MSPLIT 2
#define NC (MSPLIT*TOPS)     // 16 candidates per row
#define MRANGE (MM/MSPLIT)   // 2048

// ws layout (4-byte units): RM (NM) | CI (NQ*NC) | ENCP (NQ*DD bf16 = NQ*DD/2 u32)
#define WS_RM 0
#define WS_CI (WS_RM + NM)
#define WS_ENCP (WS_CI + NQ*NC)

#define NEG_INF (-3.402823466e38f)

typedef short bf16x8 __attribute__((ext_vector_type(8)));
typedef float f32x4 __attribute__((ext_vector_type(4)));

__device__ __forceinline__ ushort f2bf(float f) {
  unsigned u = __builtin_bit_cast(unsigned, f);
  unsigned r = u + 0x7FFFu + ((u >> 16) & 1u);   // RNE
  return (ushort)(r >> 16);
}

// ---------------- kernel 1: convert/pack (+ optional row-normalize) ----------------
// One block per 16-row tile. Packs rows into MFMA fragment order:
// frag(kt) holds, for lane l, elements X[row = l&15][k = kt*32 + (l>>4)*8 + j], j=0..7.
#define LDSW 520
__global__ __launch_bounds__(256) void k_prep(const float* __restrict__ src,
                                              ushort* __restrict__ dstP,
                                              float* __restrict__ rmOut,
                                              int normalize) {
  __shared__ float st[16 * LDSW];
  __shared__ float rs_s[16];
  const int tid = threadIdx.x;
  const int tile = blockIdx.x;
  const float* sB = src + (size_t)tile * 16 * DD;

  // stage 16x512 fp32, coalesced
  #pragma unroll
  for (int i = 0; i < 8; ++i) {
    const int idx = tid + i * 256;          // 2048 float4 slots
    const int row = idx >> 7, c4 = idx & 127;
    *(float4*)&st[row * LDSW + c4 * 4] = *(const float4*)&sB[(size_t)row * DD + c4 * 4];
  }
  __syncthreads();

  if (normalize) {
    const int row = tid >> 4, seg = tid & 15;
    float ss = 0.0f;
    #pragma unroll
    for (int i = 0; i < 8; ++i) {
      const float4 x = *(const float4*)&st[row * LDSW + seg * 32 + i * 4];
      ss += x.x*x.x + x.y*x.y + x.z*x.z + x.w*x.w;
    }
    #pragma unroll
    for (int m = 1; m < 16; m <<= 1) ss += __shfl_xor(ss, m, 64);
    if (seg == 0) {
      const float rn = 1.0f / fmaxf(sqrtf(ss), 1e-12f);
      rs_s[row] = rn;
      rmOut[tile * 16 + row] = rn;
    }
    __syncthreads();
  }

  // pack: 1024 slots (kt 0..15 x lane 0..63), 4 per thread
  #pragma unroll
  for (int i = 0; i < 4; ++i) {
    const int slot = tid + i * 256;
    const int kt = slot >> 6, lane = slot & 63;
    const int row = lane & 15;
    const int k0 = kt * 32 + (lane >> 4) * 8;
    const float sc = normalize ? rs_s[row] : 1.0f;
    const float4 x0 = *(const float4*)&st[row * LDSW + k0];
    const float4 x1 = *(const float4*)&st[row * LDSW + k0 + 4];
    uint4 o;
    o.x = (unsigned)f2bf(x0.x * sc) | ((unsigned)f2bf(x0.y * sc) << 16);
    o.y = (unsigned)f2bf(x0.z * sc) | ((unsigned)f2bf(x0.w * sc) << 16);
    o.z = (unsigned)f2bf(x1.x * sc) | ((unsigned)f2bf(x1.y * sc) << 16);
    o.w = (unsigned)f2bf(x1.z * sc) | ((unsigned)f2bf(x1.w * sc) << 16);
    ((uint4*)dstP)[(size_t)tile * 1024 + slot] = o;
  }
}

// ---------------- kernel 2: bf16 MFMA screening GEMM + per-split top-8 ----------------
// 512 blocks: (q-tile of 64) x (2 m-splits). 4 waves; wave w: q rows qbase+w*16..+15.
// Per m-chunk of 128: 8 mj-frags x 16 kc MFMAs; D layout: row=(l>>4)*4+reg, col=l&15.
__global__ __launch_bounds__(256, 2) void k_screen(const ushort* __restrict__ encP,
                                                   const ushort* __restrict__ memP,
                                                   int* __restrict__ wsci) {
  const int tid = threadIdx.x;
  const int lane = tid & 63;
  const int w = tid >> 6;
  const int qt = blockIdx.x >> 1;
  const int split = blockIdx.x & 1;
  const int qbase = qt * 64;
  const int b = qbase >> 11;
  const int rtq = (qbase >> 4) + w;
  const ushort* aB = encP + (((size_t)rtq * 16) * 64 + lane) * 8;
  const int rtm0 = b * (MM / 16) + split * (MRANGE / 16);
  const ushort* bB = memP + (((size_t)rtm0 * 16) * 64 + lane) * 8;

  float tv[4][TOPS]; int ti[4][TOPS];
  #pragma unroll
  for (int r = 0; r < 4; ++r)
    #pragma unroll
    for (int s = 0; s < TOPS; ++s) { tv[r][s] = NEG_INF; ti[r][s] = 0; }

  #pragma unroll 1
  for (int chunk = 0; chunk < MRANGE / 128; ++chunk) {
    f32x4 acc[8];
    #pragma unroll
    for (int mj = 0; mj < 8; ++mj) acc[mj] = (f32x4){0.f, 0.f, 0.f, 0.f};

    const ushort* bC = bB + (size_t)chunk * 8 * 8192;   // 8 row-tiles x 8192 shorts
    #pragma unroll 2
    for (int kc = 0; kc < 16; ++kc) {
      const bf16x8 a = *(const bf16x8*)(aB + kc * 512);
      #pragma unroll
      for (int mj = 0; mj < 8; ++mj) {
        const bf16x8 bf = *(const bf16x8*)(bC + mj * 8192 + kc * 512);
        acc[mj] = __builtin_amdgcn_mfma_f32_16x16x32_bf16(a, bf, acc[mj], 0, 0, 0);
      }
    }

    const int gm0 = split * MRANGE + chunk * 128 + (lane & 15);
    #pragma unroll
    for (int mj = 0; mj < 8; ++mj) {
      const int gm = gm0 + mj * 16;
      #pragma unroll
      for (int r = 0; r < 4; ++r) {
        float nv = acc[mj][r]; int ni = gm;
        #pragma unroll
        for (int s = 0; s < TOPS; ++s) {
          const bool g = nv > tv[r][s];
          const float ov = tv[r][s]; const int oi = ti[r][s];
          tv[r][s] = g ? nv : ov;  ti[r][s] = g ? ni : oi;
          nv = g ? ov : nv;        ni = g ? oi : ni;
        }
      }
    }
  }

  // merge per-lane lists across the 16 lanes of each row group
  #pragma unroll
  for (int step = 1; step < 16; step <<= 1) {
    #pragma unroll
    for (int r = 0; r < 4; ++r) {
      float fv[TOPS]; int fi[TOPS];
      #pragma unroll
      for (int s = 0; s < TOPS; ++s) {
        fv[s] = __shfl_xor(tv[r][s], step, 64);
        fi[s] = __shfl_xor(ti[r][s], step, 64);
      }
      #pragma unroll
      for (int s = 0; s < TOPS; ++s) {
        float nv = fv[s]; int ni = fi[s];
        #pragma unroll
        for (int s2 = 0; s2 < TOPS; ++s2) {
          const bool g = (nv > tv[r][s2]) || (nv == tv[r][s2] && ni < ti[r][s2]);
          const float ov = tv[r][s2]; const int oi = ti[r][s2];
          tv[r][s2] = g ? nv : ov;  ti[r][s2] = g ? ni : oi;
          nv = g ? ov : nv;         ni = g ? oi : ni;
        }
      }
    }
  }

  if ((lane & 15) == 0) {
    #pragma unroll
    for (int r = 0; r < 4; ++r) {
      const int q = qbase + w * 16 + (lane >> 4) * 4 + r;
      #pragma unroll
      for (int s = 0; s < TOPS; ++s)
        wsci[q * NC + split * TOPS + s] = ti[r][s];
    }
  }
}

// ---------------- kernel 3: fp64 rescore (low-pressure), exact top-5, gather, mean, add ----------------
__global__ __launch_bounds__(64) void k_out(const float* __restrict__ enc,
                                            const float* __restrict__ mem,
                                            const float* __restrict__ wsf,
                                            const int* __restrict__ wsci,
                                            float* __restrict__ out) {
  const int row = blockIdx.x;
  const int lane = threadIdx.x;
  const int b = row >> 11;

  int ci[NC]; float rm[NC];
  #pragma unroll
  for (int e = 0; e < NC; ++e) ci[e] = wsci[row * NC + e];
  #pragma unroll
  for (int e = 0; e < NC; ++e) rm[e] = wsf[WS_RM + b * MM + ci[e]];

  const float* er = enc + (size_t)row * DD;
  const float* mb = mem + (size_t)b * MM * DD;
  const int d0 = lane * 8;
  const float4 e0 = *(const float4*)(er + d0);
  const float4 e1 = *(const float4*)(er + d0 + 4);
  const double ed0 = e0.x, ed1 = e0.y, ed2 = e0.z, ed3 = e0.w;
  const double ed4 = e1.x, ed5 = e1.y, ed6 = e1.z, ed7 = e1.w;

  double fv[NC];
  #pragma unroll
  for (int g = 0; g < NC / 4; ++g) {          // groups of 4: low register pressure
    double s[4];
    #pragma unroll
    for (int e = 0; e < 4; ++e) {
      const float* mr = mb + (size_t)ci[g * 4 + e] * DD + d0;
      const float4 x0 = *(const float4*)mr;
      const float4 x1 = *(const float4*)(mr + 4);
      double t = ed0 * (double)x0.x;
      t = fma(ed1, (double)x0.y, t); t = fma(ed2, (double)x0.z, t);
      t = fma(ed3, (double)x0.w, t); t = fma(ed4, (double)x1.x, t);
      t = fma(ed5, (double)x1.y, t); t = fma(ed6, (double)x1.z, t);
      t = fma(ed7, (double)x1.w, t);
      s[e] = t;
    }
    #pragma unroll
    for (int off = 1; off < 64; off <<= 1) {
      #pragma unroll
      for (int e = 0; e < 4; ++e) s[e] += __shfl_xor(s[e], off, 64);
    }
    #pragma unroll
    for (int e = 0; e < 4; ++e) fv[g * 4 + e] = s[e] * (double)rm[g * 4 + e];
  }

  // 5 rounds of argmax by (value desc, index asc); candidates unique
  int sel[TOPK];
  #pragma unroll
  for (int t = 0; t < TOPK; ++t) {
    double bv = -1.0e300; int bi = 0x7fffffff;
    #pragma unroll
    for (int e = 0; e < NC; ++e) {
      const bool g = (fv[e] > bv) || (fv[e] == bv && ci[e] < bi);
      bv = g ? fv[e] : bv;  bi = g ? ci[e] : bi;
    }
    sel[t] = bi;
    #pragma unroll
    for (int e = 0; e < NC; ++e) fv[e] = (ci[e] == bi) ? -1.0e301 : fv[e];
  }

  float4 a0 = make_float4(0.f, 0.f, 0.f, 0.f);
  float4 a1 = make_float4(0.f, 0.f, 0.f, 0.f);
  #pragma unroll
  for (int t = 0; t < TOPK; ++t) {
    const float* mr = mb + (size_t)sel[t] * DD + d0;
    const float4 x0 = *(const float4*)mr;
    const float4 x1 = *(const float4*)(mr + 4);
    a0.x += x0.x; a0.y += x0.y; a0.z += x0.z; a0.w += x0.w;
    a1.x += x1.x; a1.y += x1.y; a1.z += x1.z; a1.w += x1.w;
  }
  float4 o0, o1;
  o0.x = e0.x + a0.x / 5.0f; o0.y = e0.y + a0.y / 5.0f;
  o0.z = e0.z + a0.z / 5.0f; o0.w = e0.w + a0.w / 5.0f;
  o1.x = e1.x + a1.x / 5.0f; o1.y = e1.y + a1.y / 5.0f;
  o1.z = e1.z + a1.z / 5.0f; o1.w = e1.w + a1.w / 5.0f;
  *(float4*)(out + (size_t)row * DD + d0)     = o0;
  *(float4*)(out + (size_t)row * DD + d0 + 4) = o1;
}

extern "C" void kernel_launch(void* const* d_in, const int* in_sizes, int n_in,
                              void* d_out, int out_size, void* d_ws, size_t ws_size,
                              hipStream_t stream) {
  (void)in_sizes; (void)n_in; (void)out_size; (void)ws_size;
  const float* enc = (const float*)d_in[0];
  const float* mem = (const float*)d_in[1];
  float* out = (float*)d_out;
  float* wsf = (float*)d_ws;
  int*   wsi = (int*)d_ws;
  ushort* encP = (ushort*)(wsf + WS_ENCP);
  ushort* memP = (ushort*)d_out;   // 32768*512 bf16 == out_size*4 bytes exactly; final kernel overwrites

  // 1) pack enc (raw) and mem (row-normalized) into MFMA fragment layout; mem norms -> ws
  k_prep<<<dim3(NQ / 16), dim3(256), 0, stream>>>(enc, encP, nullptr, 0);
  k_prep<<<dim3(NM / 16), dim3(256), 0, stream>>>(mem, memP, wsf + WS_RM, 1);

  // 2) bf16 MFMA screening: per (row, M/2-split) top-8 candidate indices
  k_screen<<<dim3((NQ / 64) * MSPLIT), dim3(256), 0, stream>>>(encP, memP, wsi + WS_CI);

  // 3) fp64 rescore of 16 candidates, exact top-5, gather, mean, add
  k_out<<<dim3(NQ), dim3(64), 0, stream>>>(enc, mem, wsf, wsi + WS_CI, out);
}

// Round 4
// 226.033 us; speedup vs baseline: 9.5670x; 1.7058x over previous
//
#include <hip/hip_runtime.h>
#include <math.h>

#define BB 8
#define LL 2048
#define MM 4096
#define DD 512
#define NQ (BB*LL)           // 16384 query rows
#define NM (BB*MM)           // 32768 memory rows
#define TOPK 5
#define TOPS 8               // kept per (row, split)
#define MSPLIT 2
#define NC (MSPLIT*TOPS)     // 16 candidates per row
#define MRANGE (MM/MSPLIT)   // 2048

// ws layout (4-byte units): RM (NM f32) | CI (NQ*NC int) | ENCP (NQ*DD bf16)
#define WS_RM 0
#define WS_CI (WS_RM + NM)
#define WS_ENCP (WS_CI + NQ*NC)

typedef short bf16x8 __attribute__((ext_vector_type(8)));
typedef float f32x16 __attribute__((ext_vector_type(16)));

__device__ __forceinline__ ushort f2bf(float f) {
  unsigned u = __builtin_bit_cast(unsigned, f);
  unsigned r = u + 0x7FFFu + ((u >> 16) & 1u);   // RNE
  return (ushort)(r >> 16);
}

// order-preserving f32 -> u32 (larger float => larger uint)
__device__ __forceinline__ unsigned keyfix(float f) {
  unsigned u = __builtin_bit_cast(unsigned, f);
  unsigned m = (unsigned)(((int)u) >> 31);
  return u ^ (m | 0x80000000u);
}

// sorted-desc top-8 insert: pure max/min cascade (2 VALU per slot)
__device__ __forceinline__ void ins8(unsigned* tv, unsigned k) {
  #pragma unroll
  for (int s = 0; s < TOPS; ++s) {
    const unsigned hi = (tv[s] > k) ? tv[s] : k;
    const unsigned lo = (tv[s] > k) ? k : tv[s];
    tv[s] = hi; k = lo;
  }
}

#define CS(i, j) { const unsigned hi = (L[i] > L[j]) ? L[i] : L[j]; \
                   const unsigned lo = (L[i] > L[j]) ? L[j] : L[i]; \
                   L[i] = hi; L[j] = lo; }

// merge two sorted-desc 8-lists -> top-8 sorted desc (bitonic)
__device__ __forceinline__ void mrg8(unsigned* a, const unsigned* b) {
  unsigned L[8];
  #pragma unroll
  for (int i = 0; i < 8; ++i) L[i] = (a[i] > b[7 - i]) ? a[i] : b[7 - i];
  CS(0,4) CS(1,5) CS(2,6) CS(3,7)
  CS(0,2) CS(1,3) CS(4,6) CS(5,7)
  CS(0,1) CS(2,3) CS(4,5) CS(6,7)
  #pragma unroll
  for (int i = 0; i < 8; ++i) a[i] = L[i];
}

// ---------------- kernel 1: pack 32-row tiles into 32x32x16-MFMA operand order ----------------
// frag(kt): lane l holds X[row=l&31][k = kt*16 + (l>>5)*8 + j], j=0..7 (8 bf16 = uint4).
// Same layout serves A (mem, row=m) and B (enc, "row"=q as the column operand).
#define LDSW 516
__global__ __launch_bounds__(256) void k_prep(const float* __restrict__ src,
                                              ushort* __restrict__ dstP,
                                              float* __restrict__ rmOut,
                                              int normalize) {
  __shared__ float st[32 * LDSW];
  __shared__ float rs_s[32];
  const int tid = threadIdx.x;
  const int tile = blockIdx.x;
  const float* sB = src + (size_t)tile * 32 * DD;

  #pragma unroll
  for (int i = 0; i < 16; ++i) {                 // 4096 float4 slots
    const int idx = tid + i * 256;
    const int row = idx >> 7, c4 = idx & 127;
    *(float4*)&st[row * LDSW + c4 * 4] = *(const float4*)&sB[(size_t)row * DD + c4 * 4];
  }
  __syncthreads();

  if (normalize) {
    const int row = tid >> 3, seg = tid & 7;     // 8 threads per row
    float ss = 0.0f;
    #pragma unroll
    for (int i = 0; i < 16; ++i) {
      const float4 x = *(const float4*)&st[row * LDSW + seg * 64 + i * 4];
      ss += x.x*x.x + x.y*x.y + x.z*x.z + x.w*x.w;
    }
    #pragma unroll
    for (int m = 1; m < 8; m <<= 1) ss += __shfl_xor(ss, m, 64);
    if (seg == 0) {
      const float rn = 1.0f / fmaxf(sqrtf(ss), 1e-12f);
      rs_s[row] = rn;
      rmOut[tile * 32 + row] = rn;
    }
    __syncthreads();
  }

  #pragma unroll
  for (int i = 0; i < 8; ++i) {                  // 2048 frag-slots (kt 0..31 x lane 0..63)
    const int slot = tid + i * 256;
    const int kt = slot >> 6, l = slot & 63;
    const int row = l & 31;
    const int k0 = kt * 16 + (l >> 5) * 8;
    const float sc = normalize ? rs_s[row] : 1.0f;
    const float4 x0 = *(const float4*)&st[row * LDSW + k0];
    const float4 x1 = *(const float4*)&st[row * LDSW + k0 + 4];
    uint4 o;
    o.x = (unsigned)f2bf(x0.x * sc) | ((unsigned)f2bf(x0.y * sc) << 16);
    o.y = (unsigned)f2bf(x0.z * sc) | ((unsigned)f2bf(x0.w * sc) << 16);
    o.z = (unsigned)f2bf(x1.x * sc) | ((unsigned)f2bf(x1.y * sc) << 16);
    o.w = (unsigned)f2bf(x1.z * sc) | ((unsigned)f2bf(x1.w * sc) << 16);
    ((uint4*)dstP)[(size_t)tile * 2048 + slot] = o;
  }
}

// ---------------- kernel 2: 32x32x16 MFMA screen, D[m][q], per-lane single top-8 list ----------------
// 256 blocks (1/CU): qt in [0,128) x split in {0,1}, XCD-swizzled so same-split blocks colocate.
// Block: 1024 thr = 16 waves; wave w: q-subtile qs=w&3 (32 q), chunk-parity p=w>>2.
// Per chunk (128 m): acc[4] f32x16; D col = lane&31 = q; rows = m (16 per lane).
__global__ __launch_bounds__(1024, 4) void k_screen(const ushort* __restrict__ encP,
                                                    const ushort* __restrict__ memP,
                                                    int* __restrict__ wsci) {
  __shared__ unsigned mlists[3][128][TOPS];      // lists of parity waves 1..3
  const int tid = threadIdx.x;
  const int l = tid & 63;
  const int w = tid >> 6;
  const int qs = w & 3, p = w >> 2;
  const int ord = blockIdx.x;
  const int lin = (ord & 7) * 32 + (ord >> 3);   // XCD-chunked remap (256 = 8*32, bijective)
  const int split = lin >> 7;
  const int qt = lin & 127;
  const int qbase = qt * 128;
  const int b = qbase >> 11;
  const ushort* bTile = encP + ((size_t)(qt * 4 + qs) * 16384) + (size_t)l * 8;
  const ushort* aBase = memP + ((size_t)(b * (MM / 32) + split * (MRANGE / 32)) * 16384)
                      + (size_t)l * 8;

  unsigned tv[TOPS];
  #pragma unroll
  for (int s = 0; s < TOPS; ++s) tv[s] = 0u;
  const int mlane = 4 * (l >> 5);

  #pragma unroll 1
  for (int t = 0; t < 4; ++t) {
    const int c = p + t * 4;                     // chunk of 128 m
    f32x16 acc[4];
    #pragma unroll
    for (int mt = 0; mt < 4; ++mt) acc[mt] = (f32x16)(0.0f);

    const ushort* aC = aBase + (size_t)c * 4 * 16384;
    #pragma unroll 4
    for (int kc = 0; kc < 32; ++kc) {
      const bf16x8 bf = *(const bf16x8*)(bTile + kc * 512);
      #pragma unroll
      for (int mt = 0; mt < 4; ++mt) {
        const bf16x8 af = *(const bf16x8*)(aC + mt * 16384 + kc * 512);
        acc[mt] = __builtin_amdgcn_mfma_f32_32x32x16_bf16(af, bf, acc[mt], 0, 0, 0);
      }
    }

    const int mg0 = split * MRANGE + c * 128 + mlane;
    const unsigned mtil0 = 4095u - (unsigned)mg0;
    #pragma unroll
    for (int mt = 0; mt < 4; ++mt) {
      #pragma unroll
      for (int r = 0; r < 16; ++r) {
        const int moff = mt * 32 + (r & 3) + 8 * (r >> 2);   // + mlane already in mg0
        const unsigned key = (keyfix(acc[mt][r]) & 0xFFFFF000u) | (mtil0 - (unsigned)moff);
        ins8(tv, key);
      }
    }
    __syncthreads();                             // keep 16 waves lockstep (L1 reuse)
  }

  // merge the two lane-halves (l <-> l+32) of each q column
  {
    unsigned ov[TOPS];
    #pragma unroll
    for (int s = 0; s < TOPS; ++s) ov[s] = (unsigned)__shfl_xor((int)tv[s], 32, 64);
    mrg8(tv, ov);
  }
  if (p != 0 && l < 32) {
    #pragma unroll
    for (int s = 0; s < TOPS; ++s) mlists[p - 1][qs * 32 + l][s] = tv[s];
  }
  __syncthreads();
  if (p == 0) {
    #pragma unroll
    for (int pp = 0; pp < 3; ++pp) {
      unsigned ov[TOPS];
      #pragma unroll
      for (int s = 0; s < TOPS; ++s) ov[s] = mlists[pp][qs * 32 + (l & 31)][s];
      mrg8(tv, ov);
    }
    if (l < 32) {
      const int q = qbase + qs * 32 + l;
      #pragma unroll
      for (int s = 0; s < TOPS; ++s)
        wsci[q * NC + split * TOPS + s] = 4095 - (int)(tv[s] & 0xFFFu);
    }
  }
}

// ---------------- kernel 3: fp64 rescore 16 candidates, exact top-5, gather, mean, add ----------------
__global__ __launch_bounds__(64) void k_out(const float* __restrict__ enc,
                                            const float* __restrict__ mem,
                                            const float* __restrict__ wsf,
                                            const int* __restrict__ wsci,
                                            float* __restrict__ out) {
  const int row = blockIdx.x;
  const int lane = threadIdx.x;
  const int b = row >> 11;

  int ci[NC]; float rm[NC];
  #pragma unroll
  for (int e = 0; e < NC; ++e) ci[e] = wsci[row * NC + e];
  #pragma unroll
  for (int e = 0; e < NC; ++e) rm[e] = wsf[WS_RM + b * MM + ci[e]];

  const float* er = enc + (size_t)row * DD;
  const float* mb = mem + (size_t)b * MM * DD;
  const int d0 = lane * 8;
  const float4 e0 = *(const float4*)(er + d0);
  const float4 e1 = *(const float4*)(er + d0 + 4);
  const double ed0 = e0.x, ed1 = e0.y, ed2 = e0.z, ed3 = e0.w;
  const double ed4 = e1.x, ed5 = e1.y, ed6 = e1.z, ed7 = e1.w;

  double fv[NC];
  #pragma unroll
  for (int g = 0; g < NC / 4; ++g) {             // groups of 4: low register pressure
    double s[4];
    #pragma unroll
    for (int e = 0; e < 4; ++e) {
      const float* mr = mb + (size_t)ci[g * 4 + e] * DD + d0;
      const float4 x0 = *(const float4*)mr;
      const float4 x1 = *(const float4*)(mr + 4);
      double t = ed0 * (double)x0.x;
      t = fma(ed1, (double)x0.y, t); t = fma(ed2, (double)x0.z, t);
      t = fma(ed3, (double)x0.w, t); t = fma(ed4, (double)x1.x, t);
      t = fma(ed5, (double)x1.y, t); t = fma(ed6, (double)x1.z, t);
      t = fma(ed7, (double)x1.w, t);
      s[e] = t;
    }
    #pragma unroll
    for (int off = 1; off < 64; off <<= 1) {
      #pragma unroll
      for (int e = 0; e < 4; ++e) s[e] += __shfl_xor(s[e], off, 64);
    }
    #pragma unroll
    for (int e = 0; e < 4; ++e) fv[g * 4 + e] = s[e] * (double)rm[g * 4 + e];
  }

  int sel[TOPK];
  #pragma unroll
  for (int t = 0; t < TOPK; ++t) {
    double bv = -1.0e300; int bi = 0x7fffffff;
    #pragma unroll
    for (int e = 0; e < NC; ++e) {
      const bool g = (fv[e] > bv) || (fv[e] == bv && ci[e] < bi);
      bv = g ? fv[e] : bv;  bi = g ? ci[e] : bi;
    }
    sel[t] = bi;
    #pragma unroll
    for (int e = 0; e < NC; ++e) fv[e] = (ci[e] == bi) ? -1.0e301 : fv[e];
  }

  float4 a0 = make_float4(0.f, 0.f, 0.f, 0.f);
  float4 a1 = make_float4(0.f, 0.f, 0.f, 0.f);
  #pragma unroll
  for (int t = 0; t < TOPK; ++t) {
    const float* mr = mb + (size_t)sel[t] * DD + d0;
    const float4 x0 = *(const float4*)mr;
    const float4 x1 = *(const float4*)(mr + 4);
    a0.x += x0.x; a0.y += x0.y; a0.z += x0.z; a0.w += x0.w;
    a1.x += x1.x; a1.y += x1.y; a1.z += x1.z; a1.w += x1.w;
  }
  float4 o0, o1;
  o0.x = e0.x + a0.x / 5.0f; o0.y = e0.y + a0.y / 5.0f;
  o0.z = e0.z + a0.z / 5.0f; o0.w = e0.w + a0.w / 5.0f;
  o1.x = e1.x + a1.x / 5.0f; o1.y = e1.y + a1.y / 5.0f;
  o1.z = e1.z + a1.z / 5.0f; o1.w = e1.w + a1.w / 5.0f;
  *(float4*)(out + (size_t)row * DD + d0)     = o0;
  *(float4*)(out + (size_t)row * DD + d0 + 4) = o1;
}

extern "C" void kernel_launch(void* const* d_in, const int* in_sizes, int n_in,
                              void* d_out, int out_size, void* d_ws, size_t ws_size,
                              hipStream_t stream) {
  (void)in_sizes; (void)n_in; (void)out_size; (void)ws_size;
  const float* enc = (const float*)d_in[0];
  const float* mem = (const float*)d_in[1];
  float* out = (float*)d_out;
  float* wsf = (float*)d_ws;
  int*   wsi = (int*)d_ws;
  ushort* encP = (ushort*)(wsf + WS_ENCP);
  ushort* memP = (ushort*)d_out;   // NM*DD bf16 == out bytes exactly; k_out overwrites

  // 1) pack enc (raw) and mem (row-normalized) into 32x32x16 MFMA operand layout
  k_prep<<<dim3(NQ / 32), dim3(256), 0, stream>>>(enc, encP, nullptr, 0);
  k_prep<<<dim3(NM / 32), dim3(256), 0, stream>>>(mem, memP, wsf + WS_RM, 1);

  // 2) MFMA screening: per (row, M/2-split) top-8 candidate indices (packed-key cascade)
  k_screen<<<dim3(256), dim3(1024), 0, stream>>>(encP, memP, wsi + WS_CI);

  // 3) fp64 rescore of 16 candidates, exact top-5, gather, mean, add
  k_out<<<dim3(NQ), dim3(64), 0, stream>>>(enc, mem, wsf, wsi + WS_CI, out);
}

// Round 5
// 225.330 us; speedup vs baseline: 9.5969x; 1.0031x over previous
//
#include <hip/hip_runtime.h>
#include <math.h>

#define BB 8
#define LL 2048
#define MM 4096
#define DD 512
#define NQ (BB*LL)           // 16384 query rows
#define NM (BB*MM)           // 32768 memory rows
#define TOPK 5
#define TOPS 8               // kept per (row, split)
#define MSPLIT 2
#define NC (MSPLIT*TOPS)     // 16 candidates per row
#define MRANGE (MM/MSPLIT)   // 2048

// ws layout (4-byte units): RM (NM f32) | CI (NQ*NC int) | ENCP (NQ*DD bf16)
#define WS_RM 0
#define WS_CI (WS_RM + NM)
#define WS_ENCP (WS_CI + NQ*NC)

typedef short bf16x8 __attribute__((ext_vector_type(8)));
typedef float f32x16 __attribute__((ext_vector_type(16)));

__device__ __forceinline__ ushort f2bf(float f) {
  unsigned u = __builtin_bit_cast(unsigned, f);
  unsigned r = u + 0x7FFFu + ((u >> 16) & 1u);   // RNE
  return (ushort)(r >> 16);
}

// chunk-local sorted-desc top-5 insert: 2 VALU per slot
__device__ __forceinline__ void ins5(unsigned* tv, unsigned k) {
  #pragma unroll
  for (int s = 0; s < 5; ++s) {
    const unsigned hi = (tv[s] > k) ? tv[s] : k;
    const unsigned lo = (tv[s] > k) ? k : tv[s];
    tv[s] = hi; k = lo;
  }
}

#define CS(i, j) { const unsigned hi = (L[i] > L[j]) ? L[i] : L[j]; \
                   const unsigned lo = (L[i] > L[j]) ? L[j] : L[i]; \
                   L[i] = hi; L[j] = lo; }

// merge two sorted-desc 8-lists -> top-8 sorted desc (bitonic)
__device__ __forceinline__ void mrg8(unsigned* a, const unsigned* b) {
  unsigned L[8];
  #pragma unroll
  for (int i = 0; i < 8; ++i) L[i] = (a[i] > b[7 - i]) ? a[i] : b[7 - i];
  CS(0,4) CS(1,5) CS(2,6) CS(3,7)
  CS(0,2) CS(1,3) CS(4,6) CS(5,7)
  CS(0,1) CS(2,3) CS(4,5) CS(6,7)
  #pragma unroll
  for (int i = 0; i < 8; ++i) a[i] = L[i];
}

// ---------------- kernel 1: pack 32-row tiles into 32x32x16-MFMA operand order ----------------
// frag(kt): lane l holds X[row=l&31][k = kt*16 + (l>>5)*8 + j], j=0..7 (8 bf16 = uint4).
#define LDSW 516
__global__ __launch_bounds__(256) void k_prep(const float* __restrict__ src,
                                              ushort* __restrict__ dstP,
                                              float* __restrict__ rmOut,
                                              int normalize) {
  __shared__ float st[32 * LDSW];
  __shared__ float rs_s[32];
  const int tid = threadIdx.x;
  const int tile = blockIdx.x;
  const float* sB = src + (size_t)tile * 32 * DD;

  #pragma unroll
  for (int i = 0; i < 16; ++i) {                 // 4096 float4 slots
    const int idx = tid + i * 256;
    const int row = idx >> 7, c4 = idx & 127;
    *(float4*)&st[row * LDSW + c4 * 4] = *(const float4*)&sB[(size_t)row * DD + c4 * 4];
  }
  __syncthreads();

  if (normalize) {
    const int row = tid >> 3, seg = tid & 7;     // 8 threads per row
    float ss = 0.0f;
    #pragma unroll
    for (int i = 0; i < 16; ++i) {
      const float4 x = *(const float4*)&st[row * LDSW + seg * 64 + i * 4];
      ss += x.x*x.x + x.y*x.y + x.z*x.z + x.w*x.w;
    }
    #pragma unroll
    for (int m = 1; m < 8; m <<= 1) ss += __shfl_xor(ss, m, 64);
    if (seg == 0) {
      const float rn = 1.0f / fmaxf(sqrtf(ss), 1e-12f);
      rs_s[row] = rn;
      rmOut[tile * 32 + row] = rn;
    }
    __syncthreads();
  }

  #pragma unroll
  for (int i = 0; i < 8; ++i) {                  // 2048 frag-slots (kt 0..31 x lane 0..63)
    const int slot = tid + i * 256;
    const int kt = slot >> 6, l = slot & 63;
    const int row = l & 31;
    const int k0 = kt * 16 + (l >> 5) * 8;
    const float sc = normalize ? rs_s[row] : 1.0f;
    const float4 x0 = *(const float4*)&st[row * LDSW + k0];
    const float4 x1 = *(const float4*)&st[row * LDSW + k0 + 4];
    uint4 o;
    o.x = (unsigned)f2bf(x0.x * sc) | ((unsigned)f2bf(x0.y * sc) << 16);
    o.y = (unsigned)f2bf(x0.z * sc) | ((unsigned)f2bf(x0.w * sc) << 16);
    o.z = (unsigned)f2bf(x1.x * sc) | ((unsigned)f2bf(x1.y * sc) << 16);
    o.w = (unsigned)f2bf(x1.z * sc) | ((unsigned)f2bf(x1.w * sc) << 16);
    ((uint4*)dstP)[(size_t)tile * 2048 + slot] = o;
  }
}

// ---------------- kernel 2: 32x32x16 MFMA screen, wave-tile 64m x 64q ----------------
// grid 512 = 256 qt x 2 split (XCD-remapped); block 512 thr = 8 waves.
// Wave w owns m-tiles {t*16 + w*2 + mt}; all waves share the block's 64 q (2 enc tiles).
// Key: bits(acc+28)&~0x7FF | (2047 - m_in_split)  (monotone, tie -> smaller m).
__global__ __launch_bounds__(512, 4) void k_screen(const ushort* __restrict__ encP,
                                                   const ushort* __restrict__ memP,
                                                   int* __restrict__ wsci) {
  __shared__ unsigned mlists[7][32][2][TOPS];
  const int tid = threadIdx.x;
  const int l = tid & 63;
  const int w = tid >> 6;                        // 0..7
  const int ord = blockIdx.x;
  const int lin = (ord & 7) * 64 + (ord >> 3);   // 512 = 8*64, bijective XCD remap
  const int split = lin >> 8;
  const int qt = lin & 255;
  const int qbase = qt * 64;
  const int b = qbase >> 11;
  const ushort* bT0 = encP + ((size_t)(qt * 2 + 0) * 16384) + (size_t)l * 8;
  const ushort* bT1 = encP + ((size_t)(qt * 2 + 1) * 16384) + (size_t)l * 8;
  const int atile0 = b * (MM / 32) + split * (MRANGE / 32);

  unsigned tv[2][TOPS];
  #pragma unroll
  for (int qs = 0; qs < 2; ++qs)
    #pragma unroll
    for (int s = 0; s < TOPS; ++s) tv[qs][s] = 0u;

  #pragma unroll 1
  for (int t = 0; t < 4; ++t) {
    unsigned bk[2][5];
    #pragma unroll
    for (int qs = 0; qs < 2; ++qs)
      #pragma unroll
      for (int s = 0; s < 5; ++s) bk[qs][s] = 0u;

    #pragma unroll
    for (int mt = 0; mt < 2; ++mt) {
      f32x16 acc0 = (f32x16)(0.0f);
      f32x16 acc1 = (f32x16)(0.0f);
      const ushort* aT = memP + (size_t)(atile0 + t * 16 + w * 2 + mt) * 16384
                       + (size_t)l * 8;
      #pragma unroll 2
      for (int kc = 0; kc < 32; ++kc) {
        const bf16x8 af = *(const bf16x8*)(aT + kc * 512);
        const bf16x8 b0 = *(const bf16x8*)(bT0 + kc * 512);
        const bf16x8 b1 = *(const bf16x8*)(bT1 + kc * 512);
        acc0 = __builtin_amdgcn_mfma_f32_32x32x16_bf16(af, b0, acc0, 0, 0, 0);
        acc1 = __builtin_amdgcn_mfma_f32_32x32x16_bf16(af, b1, acc1, 0, 0, 0);
      }
      // m within split: t*512 + w*64 + mt*32 + 4*(l>>5) + (r&3) + 8*(r>>2)
      const unsigned ibase = 2047u - (unsigned)(t * 512 + w * 64 + mt * 32 + 4 * (l >> 5));
      #pragma unroll
      for (int r = 0; r < 16; ++r) {
        const unsigned ioff = (unsigned)((r & 3) + 8 * (r >> 2));
        const float f0 = acc0[r] + 28.0f;
        const unsigned k0 = (__builtin_bit_cast(unsigned, f0) & 0xFFFFF800u) | (ibase - ioff);
        ins5(bk[0], k0);
        const float f1 = acc1[r] + 28.0f;
        const unsigned k1 = (__builtin_bit_cast(unsigned, f1) & 0xFFFFF800u) | (ibase - ioff);
        ins5(bk[1], k1);
      }
    }
    #pragma unroll
    for (int qs = 0; qs < 2; ++qs) {
      const unsigned bb[8] = {bk[qs][0], bk[qs][1], bk[qs][2], bk[qs][3], bk[qs][4],
                              0u, 0u, 0u};
      mrg8(tv[qs], bb);
    }
    __syncthreads();                             // keep waves lockstep (B-frag L1 reuse)
  }

  // merge lane-halves (l <-> l+32): both halves end with the full per-q list
  #pragma unroll
  for (int qs = 0; qs < 2; ++qs) {
    unsigned ov[TOPS];
    #pragma unroll
    for (int s = 0; s < TOPS; ++s) ov[s] = (unsigned)__shfl_xor((int)tv[qs][s], 32, 64);
    mrg8(tv[qs], ov);
  }

  if (w > 0 && l < 32) {
    #pragma unroll
    for (int qs = 0; qs < 2; ++qs) {
      uint4* dst = (uint4*)&mlists[w - 1][l][qs][0];
      dst[0] = make_uint4(tv[qs][0], tv[qs][1], tv[qs][2], tv[qs][3]);
      dst[1] = make_uint4(tv[qs][4], tv[qs][5], tv[qs][6], tv[qs][7]);
    }
  }
  __syncthreads();
  if (w == 0) {
    #pragma unroll
    for (int pp = 0; pp < 7; ++pp) {
      #pragma unroll
      for (int qs = 0; qs < 2; ++qs) {
        unsigned ov[TOPS];
        #pragma unroll
        for (int s = 0; s < TOPS; ++s) ov[s] = mlists[pp][l & 31][qs][s];
        mrg8(tv[qs], ov);
      }
    }
    if (l < 32) {
      #pragma unroll
      for (int qs = 0; qs < 2; ++qs) {
        const int q = qbase + qs * 32 + l;
        #pragma unroll
        for (int s = 0; s < TOPS; ++s) {
          const int m = split * MRANGE + 2047 - (int)(tv[qs][s] & 0x7FFu);
          wsci[q * NC + split * TOPS + s] = m;
        }
      }
    }
  }
}

// ---------------- kernel 3: fp64 rescore 16 candidates, exact top-5, gather, mean, add ----------------
__global__ __launch_bounds__(64) void k_out(const float* __restrict__ enc,
                                            const float* __restrict__ mem,
                                            const float* __restrict__ wsf,
                                            const int* __restrict__ wsci,
                                            float* __restrict__ out) {
  const int row = blockIdx.x;
  const int lane = threadIdx.x;
  const int b = row >> 11;

  int ci[NC]; float rm[NC];
  #pragma unroll
  for (int e = 0; e < NC; ++e) ci[e] = wsci[row * NC + e];
  #pragma unroll
  for (int e = 0; e < NC; ++e) rm[e] = wsf[WS_RM + b * MM + ci[e]];

  const float* er = enc + (size_t)row * DD;
  const float* mb = mem + (size_t)b * MM * DD;
  const int d0 = lane * 8;
  const float4 e0 = *(const float4*)(er + d0);
  const float4 e1 = *(const float4*)(er + d0 + 4);
  const double ed0 = e0.x, ed1 = e0.y, ed2 = e0.z, ed3 = e0.w;
  const double ed4 = e1.x, ed5 = e1.y, ed6 = e1.z, ed7 = e1.w;

  double fv[NC];
  #pragma unroll
  for (int g = 0; g < NC / 4; ++g) {             // groups of 4: low register pressure
    double s[4];
    #pragma unroll
    for (int e = 0; e < 4; ++e) {
      const float* mr = mb + (size_t)ci[g * 4 + e] * DD + d0;
      const float4 x0 = *(const float4*)mr;
      const float4 x1 = *(const float4*)(mr + 4);
      double t = ed0 * (double)x0.x;
      t = fma(ed1, (double)x0.y, t); t = fma(ed2, (double)x0.z, t);
      t = fma(ed3, (double)x0.w, t); t = fma(ed4, (double)x1.x, t);
      t = fma(ed5, (double)x1.y, t); t = fma(ed6, (double)x1.z, t);
      t = fma(ed7, (double)x1.w, t);
      s[e] = t;
    }
    #pragma unroll
    for (int off = 1; off < 64; off <<= 1) {
      #pragma unroll
      for (int e = 0; e < 4; ++e) s[e] += __shfl_xor(s[e], off, 64);
    }
    #pragma unroll
    for (int e = 0; e < 4; ++e) fv[g * 4 + e] = s[e] * (double)rm[g * 4 + e];
  }

  int sel[TOPK];
  #pragma unroll
  for (int t = 0; t < TOPK; ++t) {
    double bv = -1.0e300; int bi = 0x7fffffff;
    #pragma unroll
    for (int e = 0; e < NC; ++e) {
      const bool g = (fv[e] > bv) || (fv[e] == bv && ci[e] < bi);
      bv = g ? fv[e] : bv;  bi = g ? ci[e] : bi;
    }
    sel[t] = bi;
    #pragma unroll
    for (int e = 0; e < NC; ++e) fv[e] = (ci[e] == bi) ? -1.0e301 : fv[e];
  }

  float4 a0 = make_float4(0.f, 0.f, 0.f, 0.f);
  float4 a1 = make_float4(0.f, 0.f, 0.f, 0.f);
  #pragma unroll
  for (int t = 0; t < TOPK; ++t) {
    const float* mr = mb + (size_t)sel[t] * DD + d0;
    const float4 x0 = *(const float4*)mr;
    const float4 x1 = *(const float4*)(mr + 4);
    a0.x += x0.x; a0.y += x0.y; a0.z += x0.z; a0.w += x0.w;
    a1.x += x1.x; a1.y += x1.y; a1.z += x1.z; a1.w += x1.w;
  }
  float4 o0, o1;
  o0.x = e0.x + a0.x / 5.0f; o0.y = e0.y + a0.y / 5.0f;
  o0.z = e0.z + a0.z / 5.0f; o0.w = e0.w + a0.w / 5.0f;
  o1.x = e1.x + a1.x / 5.0f; o1.y = e1.y + a1.y / 5.0f;
  o1.z = e1.z + a1.z / 5.0f; o1.w = e1.w + a1.w / 5.0f;
  *(float4*)(out + (size_t)row * DD + d0)     = o0;
  *(float4*)(out + (size_t)row * DD + d0 + 4) = o1;
}

extern "C" void kernel_launch(void* const* d_in, const int* in_sizes, int n_in,
                              void* d_out, int out_size, void* d_ws, size_t ws_size,
                              hipStream_t stream) {
  (void)in_sizes; (void)n_in; (void)out_size; (void)ws_size;
  const float* enc = (const float*)d_in[0];
  const float* mem = (const float*)d_in[1];
  float* out = (float*)d_out;
  float* wsf = (float*)d_ws;
  int*   wsi = (int*)d_ws;
  ushort* encP = (ushort*)(wsf + WS_ENCP);
  ushort* memP = (ushort*)d_out;   // NM*DD bf16 == out bytes exactly; k_out overwrites

  // 1) pack enc (raw) and mem (row-normalized) into 32x32x16 MFMA operand layout
  k_prep<<<dim3(NQ / 32), dim3(256), 0, stream>>>(enc, encP, nullptr, 0);
  k_prep<<<dim3(NM / 32), dim3(256), 0, stream>>>(mem, memP, wsf + WS_RM, 1);

  // 2) MFMA screening: per (row, M/2-split) top-8 candidate indices
  k_screen<<<dim3(512), dim3(512), 0, stream>>>(encP, memP, wsi + WS_CI);

  // 3) fp64 rescore of 16 candidates, exact top-5, gather, mean, add
  k_out<<<dim3(NQ), dim3(64), 0, stream>>>(enc, mem, wsf, wsi + WS_CI, out);
}

// Round 6
// 197.777 us; speedup vs baseline: 10.9338x; 1.1393x over previous
//
#include <hip/hip_runtime.h>
#include <math.h>

#define BB 8
#define LL 2048
#define MM 4096
#define DD 512
#define NQ (BB*LL)           // 16384 query rows
#define NM (BB*MM)           // 32768 memory rows
#define TOPK 5
#define TOPS 8               // kept per (row, split)
#define MSPLIT 2
#define NC (MSPLIT*TOPS)     // 16 candidates per row
#define MRANGE (MM/MSPLIT)   // 2048

// ws layout (4-byte units): RM (NM f32) | CI (NQ*NC int) | ENCP (NQ*DD bf16)
#define WS_RM 0
#define WS_CI (WS_RM + NM)
#define WS_ENCP (WS_CI + NQ*NC)

typedef short bf16x8 __attribute__((ext_vector_type(8)));
typedef float f32x16 __attribute__((ext_vector_type(16)));

__device__ __forceinline__ ushort f2bf(float f) {
  unsigned u = __builtin_bit_cast(unsigned, f);
  unsigned r = u + 0x7FFFu + ((u >> 16) & 1u);   // RNE
  return (ushort)(r >> 16);
}

// chunk-local sorted-desc top-5 insert: 2 VALU per slot
__device__ __forceinline__ void ins5(unsigned* tv, unsigned k) {
  #pragma unroll
  for (int s = 0; s < 5; ++s) {
    const unsigned hi = (tv[s] > k) ? tv[s] : k;
    const unsigned lo = (tv[s] > k) ? k : tv[s];
    tv[s] = hi; k = lo;
  }
}

#define CS(i, j) { const unsigned hi = (L[i] > L[j]) ? L[i] : L[j]; \
                   const unsigned lo = (L[i] > L[j]) ? L[j] : L[i]; \
                   L[i] = hi; L[j] = lo; }

// merge two sorted-desc 8-lists -> top-8 sorted desc (bitonic)
__device__ __forceinline__ void mrg8(unsigned* a, const unsigned* b) {
  unsigned L[8];
  #pragma unroll
  for (int i = 0; i < 8; ++i) L[i] = (a[i] > b[7 - i]) ? a[i] : b[7 - i];
  CS(0,4) CS(1,5) CS(2,6) CS(3,7)
  CS(0,2) CS(1,3) CS(4,6) CS(5,7)
  CS(0,1) CS(2,3) CS(4,5) CS(6,7)
  #pragma unroll
  for (int i = 0; i < 8; ++i) a[i] = L[i];
}

// ---------------- kernel 1: pack 32-row tiles into 32x32x16-MFMA operand order ----------------
// frag(kt): lane l holds X[row=l&31][k = kt*16 + (l>>5)*8 + j], j=0..7 (8 bf16 = uint4).
#define LDSW 516
__global__ __launch_bounds__(256) void k_prep(const float* __restrict__ src,
                                              ushort* __restrict__ dstP,
                                              float* __restrict__ rmOut,
                                              int normalize) {
  __shared__ float st[32 * LDSW];
  __shared__ float rs_s[32];
  const int tid = threadIdx.x;
  const int tile = blockIdx.x;
  const float* sB = src + (size_t)tile * 32 * DD;

  #pragma unroll
  for (int i = 0; i < 16; ++i) {                 // 4096 float4 slots
    const int idx = tid + i * 256;
    const int row = idx >> 7, c4 = idx & 127;
    *(float4*)&st[row * LDSW + c4 * 4] = *(const float4*)&sB[(size_t)row * DD + c4 * 4];
  }
  __syncthreads();

  if (normalize) {
    const int row = tid >> 3, seg = tid & 7;     // 8 threads per row
    float ss = 0.0f;
    #pragma unroll
    for (int i = 0; i < 16; ++i) {
      const float4 x = *(const float4*)&st[row * LDSW + seg * 64 + i * 4];
      ss += x.x*x.x + x.y*x.y + x.z*x.z + x.w*x.w;
    }
    #pragma unroll
    for (int m = 1; m < 8; m <<= 1) ss += __shfl_xor(ss, m, 64);
    if (seg == 0) {
      const float rn = 1.0f / fmaxf(sqrtf(ss), 1e-12f);
      rs_s[row] = rn;
      rmOut[tile * 32 + row] = rn;
    }
    __syncthreads();
  }

  #pragma unroll
  for (int i = 0; i < 8; ++i) {                  // 2048 frag-slots (kt 0..31 x lane 0..63)
    const int slot = tid + i * 256;
    const int kt = slot >> 6, l = slot & 63;
    const int row = l & 31;
    const int k0 = kt * 16 + (l >> 5) * 8;
    const float sc = normalize ? rs_s[row] : 1.0f;
    const float4 x0 = *(const float4*)&st[row * LDSW + k0];
    const float4 x1 = *(const float4*)&st[row * LDSW + k0 + 4];
    uint4 o;
    o.x = (unsigned)f2bf(x0.x * sc) | ((unsigned)f2bf(x0.y * sc) << 16);
    o.y = (unsigned)f2bf(x0.z * sc) | ((unsigned)f2bf(x0.w * sc) << 16);
    o.z = (unsigned)f2bf(x1.x * sc) | ((unsigned)f2bf(x1.y * sc) << 16);
    o.w = (unsigned)f2bf(x1.z * sc) | ((unsigned)f2bf(x1.w * sc) << 16);
    ((uint4*)dstP)[(size_t)tile * 2048 + slot] = o;
  }
}

// ---------------- kernel 2: 32x32x16 MFMA screen, 2m x 2q register tile, B in LDS ----------------
// grid 512 = 256 qt x 2 split (XCD-remapped); block 512 thr = 8 waves; NO per-phase barrier.
// Block covers 64 q (2 enc tiles, LDS-staged once) x 2048 m (split).
// Wave w, iter t in [0,4): m-tiles atile0 + t*16 + w*2 + {0,1}.
// Key: bits(acc+28)&~0x7FF | (2047 - m_in_split)  (monotone, tie -> smaller m).
__global__ __launch_bounds__(512, 4) void k_screen(const ushort* __restrict__ encP,
                                                   const ushort* __restrict__ memP,
                                                   int* __restrict__ wsci) {
  __shared__ uint4 ebuf[4096];                   // 64 KB: 2 enc tiles; reused for merge lists
  unsigned* ml = (unsigned*)ebuf;                // [w-1][qs*32+l][s] linear, after final barrier
  const int tid = threadIdx.x;
  const int l = tid & 63;
  const int w = tid >> 6;                        // 0..7
  const int ord = blockIdx.x;
  const int lin = (ord & 7) * 64 + (ord >> 3);   // 512 = 8*64, bijective XCD remap
  const int split = lin >> 8;
  const int qt = lin & 255;
  const int qbase = qt * 64;
  const int b = qbase >> 11;
  const int atile0 = b * (MM / 32) + split * (MRANGE / 32);

  // stage both enc tiles (contiguous 64 KB) into LDS
  {
    const uint4* src = (const uint4*)encP + (size_t)(qt * 2) * 2048;
    #pragma unroll
    for (int i = 0; i < 8; ++i) ebuf[tid + i * 512] = src[tid + i * 512];
  }
  __syncthreads();

  unsigned tv[2][TOPS];
  #pragma unroll
  for (int qs = 0; qs < 2; ++qs)
    #pragma unroll
    for (int s = 0; s < TOPS; ++s) tv[qs][s] = 0u;

  #pragma unroll 1
  for (int t = 0; t < 4; ++t) {
    unsigned bk[2][5];
    #pragma unroll
    for (int qs = 0; qs < 2; ++qs)
      #pragma unroll
      for (int s = 0; s < 5; ++s) bk[qs][s] = 0u;

    f32x16 acc00 = (f32x16)(0.0f), acc01 = (f32x16)(0.0f);
    f32x16 acc10 = (f32x16)(0.0f), acc11 = (f32x16)(0.0f);
    const ushort* aT = memP + (size_t)(atile0 + t * 16 + w * 2) * 16384 + (size_t)l * 8;

    #pragma unroll 2
    for (int kc = 0; kc < 32; ++kc) {
      const bf16x8 a0 = *(const bf16x8*)(aT + kc * 512);
      const bf16x8 a1 = *(const bf16x8*)(aT + 16384 + kc * 512);
      const bf16x8 b0 = *(const bf16x8*)&ebuf[kc * 64 + l];
      const bf16x8 b1 = *(const bf16x8*)&ebuf[2048 + kc * 64 + l];
      acc00 = __builtin_amdgcn_mfma_f32_32x32x16_bf16(a0, b0, acc00, 0, 0, 0);
      acc01 = __builtin_amdgcn_mfma_f32_32x32x16_bf16(a0, b1, acc01, 0, 0, 0);
      acc10 = __builtin_amdgcn_mfma_f32_32x32x16_bf16(a1, b0, acc10, 0, 0, 0);
      acc11 = __builtin_amdgcn_mfma_f32_32x32x16_bf16(a1, b1, acc11, 0, 0, 0);
    }

    // insert 2mt x 2q x 16 values into per-t buckets
    const unsigned ib0 = 2047u - (unsigned)(t * 512 + w * 64 + 4 * (l >> 5));
    #pragma unroll
    for (int r = 0; r < 16; ++r) {
      const unsigned idx = ib0 - (unsigned)((r & 3) + 8 * (r >> 2));
      const float f00 = acc00[r] + 28.0f;
      ins5(bk[0], (__builtin_bit_cast(unsigned, f00) & 0xFFFFF800u) | idx);
      const float f01 = acc01[r] + 28.0f;
      ins5(bk[1], (__builtin_bit_cast(unsigned, f01) & 0xFFFFF800u) | idx);
      const float f10 = acc10[r] + 28.0f;
      ins5(bk[0], (__builtin_bit_cast(unsigned, f10) & 0xFFFFF800u) | (idx - 32u));
      const float f11 = acc11[r] + 28.0f;
      ins5(bk[1], (__builtin_bit_cast(unsigned, f11) & 0xFFFFF800u) | (idx - 32u));
    }

    #pragma unroll
    for (int qs = 0; qs < 2; ++qs) {
      const unsigned bb[8] = {bk[qs][0], bk[qs][1], bk[qs][2], bk[qs][3], bk[qs][4],
                              0u, 0u, 0u};
      mrg8(tv[qs], bb);
    }
  }

  // merge lane-halves (l <-> l+32): both halves end with the full per-q list
  #pragma unroll
  for (int qs = 0; qs < 2; ++qs) {
    unsigned ov[TOPS];
    #pragma unroll
    for (int s = 0; s < TOPS; ++s) ov[s] = (unsigned)__shfl_xor((int)tv[qs][s], 32, 64);
    mrg8(tv[qs], ov);
  }

  __syncthreads();                               // all ebuf reads done; reuse LDS for lists
  if (w > 0 && l < 32) {
    #pragma unroll
    for (int qs = 0; qs < 2; ++qs)
      #pragma unroll
      for (int s = 0; s < TOPS; ++s)
        ml[((w - 1) * 64 + qs * 32 + l) * 8 + s] = tv[qs][s];
  }
  __syncthreads();
  if (w == 0) {
    #pragma unroll
    for (int pp = 0; pp < 7; ++pp) {
      #pragma unroll
      for (int qs = 0; qs < 2; ++qs) {
        unsigned ov[TOPS];
        #pragma unroll
        for (int s = 0; s < TOPS; ++s) ov[s] = ml[(pp * 64 + qs * 32 + (l & 31)) * 8 + s];
        mrg8(tv[qs], ov);
      }
    }
    if (l < 32) {
      #pragma unroll
      for (int qs = 0; qs < 2; ++qs) {
        const int q = qbase + qs * 32 + l;
        #pragma unroll
        for (int s = 0; s < TOPS; ++s) {
          const int m = split * MRANGE + 2047 - (int)(tv[qs][s] & 0x7FFu);
          wsci[q * NC + split * TOPS + s] = m;
        }
      }
    }
  }
}

// ---------------- kernel 3: fp64 rescore 16 candidates, exact top-5, gather, mean, add ----------------
__global__ __launch_bounds__(64) void k_out(const float* __restrict__ enc,
                                            const float* __restrict__ mem,
                                            const float* __restrict__ wsf,
                                            const int* __restrict__ wsci,
                                            float* __restrict__ out) {
  const int row = blockIdx.x;
  const int lane = threadIdx.x;
  const int b = row >> 11;

  int ci[NC]; float rm[NC];
  #pragma unroll
  for (int e = 0; e < NC; ++e) ci[e] = wsci[row * NC + e];
  #pragma unroll
  for (int e = 0; e < NC; ++e) rm[e] = wsf[WS_RM + b * MM + ci[e]];

  const float* er = enc + (size_t)row * DD;
  const float* mb = mem + (size_t)b * MM * DD;
  const int d0 = lane * 8;
  const float4 e0 = *(const float4*)(er + d0);
  const float4 e1 = *(const float4*)(er + d0 + 4);
  const double ed0 = e0.x, ed1 = e0.y, ed2 = e0.z, ed3 = e0.w;
  const double ed4 = e1.x, ed5 = e1.y, ed6 = e1.z, ed7 = e1.w;

  double fv[NC];
  #pragma unroll
  for (int g = 0; g < NC / 4; ++g) {             // groups of 4: low register pressure
    double s[4];
    #pragma unroll
    for (int e = 0; e < 4; ++e) {
      const float* mr = mb + (size_t)ci[g * 4 + e] * DD + d0;
      const float4 x0 = *(const float4*)mr;
      const float4 x1 = *(const float4*)(mr + 4);
      double t = ed0 * (double)x0.x;
      t = fma(ed1, (double)x0.y, t); t = fma(ed2, (double)x0.z, t);
      t = fma(ed3, (double)x0.w, t); t = fma(ed4, (double)x1.x, t);
      t = fma(ed5, (double)x1.y, t); t = fma(ed6, (double)x1.z, t);
      t = fma(ed7, (double)x1.w, t);
      s[e] = t;
    }
    #pragma unroll
    for (int off = 1; off < 64; off <<= 1) {
      #pragma unroll
      for (int e = 0; e < 4; ++e) s[e] += __shfl_xor(s[e], off, 64);
    }
    #pragma unroll
    for (int e = 0; e < 4; ++e) fv[g * 4 + e] = s[e] * (double)rm[g * 4 + e];
  }

  int sel[TOPK];
  #pragma unroll
  for (int t = 0; t < TOPK; ++t) {
    double bv = -1.0e300; int bi = 0x7fffffff;
    #pragma unroll
    for (int e = 0; e < NC; ++e) {
      const bool g = (fv[e] > bv) || (fv[e] == bv && ci[e] < bi);
      bv = g ? fv[e] : bv;  bi = g ? ci[e] : bi;
    }
    sel[t] = bi;
    #pragma unroll
    for (int e = 0; e < NC; ++e) fv[e] = (ci[e] == bi) ? -1.0e301 : fv[e];
  }

  float4 a0 = make_float4(0.f, 0.f, 0.f, 0.f);
  float4 a1 = make_float4(0.f, 0.f, 0.f, 0.f);
  #pragma unroll
  for (int t = 0; t < TOPK; ++t) {
    const float* mr = mb + (size_t)sel[t] * DD + d0;
    const float4 x0 = *(const float4*)mr;
    const float4 x1 = *(const float4*)(mr + 4);
    a0.x += x0.x; a0.y += x0.y; a0.z += x0.z; a0.w += x0.w;
    a1.x += x1.x; a1.y += x1.y; a1.z += x1.z; a1.w += x1.w;
  }
  float4 o0, o1;
  o0.x = e0.x + a0.x / 5.0f; o0.y = e0.y + a0.y / 5.0f;
  o0.z = e0.z + a0.z / 5.0f; o0.w = e0.w + a0.w / 5.0f;
  o1.x = e1.x + a1.x / 5.0f; o1.y = e1.y + a1.y / 5.0f;
  o1.z = e1.z + a1.z / 5.0f; o1.w = e1.w + a1.w / 5.0f;
  *(float4*)(out + (size_t)row * DD + d0)     = o0;
  *(float4*)(out + (size_t)row * DD + d0 + 4) = o1;
}

extern "C" void kernel_launch(void* const* d_in, const int* in_sizes, int n_in,
                              void* d_out, int out_size, void* d_ws, size_t ws_size,
                              hipStream_t stream) {
  (void)in_sizes; (void)n_in; (void)out_size; (void)ws_size;
  const float* enc = (const float*)d_in[0];
  const float* mem = (const float*)d_in[1];
  float* out = (float*)d_out;
  float* wsf = (float*)d_ws;
  int*   wsi = (int*)d_ws;
  ushort* encP = (ushort*)(wsf + WS_ENCP);
  ushort* memP = (ushort*)d_out;   // NM*DD bf16 == out bytes exactly; k_out overwrites

  // 1) pack enc (raw) and mem (row-normalized) into 32x32x16 MFMA operand layout
  k_prep<<<dim3(NQ / 32), dim3(256), 0, stream>>>(enc, encP, nullptr, 0);
  k_prep<<<dim3(NM / 32), dim3(256), 0, stream>>>(mem, memP, wsf + WS_RM, 1);

  // 2) MFMA screening: per (row, M/2-split) top-8 candidate indices
  k_screen<<<dim3(512), dim3(512), 0, stream>>>(encP, memP, wsi + WS_CI);

  // 3) fp64 rescore of 16 candidates, exact top-5, gather, mean, add
  k_out<<<dim3(NQ), dim3(64), 0, stream>>>(enc, mem, wsf, wsi + WS_CI, out);
}